// Round 1
// baseline (90.367 us; speedup 1.0000x reference)
//
#include <hip/hip_runtime.h>
#include <math.h>

// Problem constants (from reference)
#define XS 540
#define YS 540
#define NB 4            // batch
#define NBOX 64
#define TILE 36         // 36x36 cells per block
#define TPX 15          // 540 / 36
#define CELLS_PER_TILE (TILE * TILE)

// d_ws layout: double acc[12] = { s1[4] (w*bce*valid), s2[4] (focal*bce*valid), cnt[4] }

__global__ __launch_bounds__(256) void hmdl_main(
    const float* __restrict__ logits,   // [4,1,540,540]
    const float* __restrict__ boxes,    // [4,64,7]
    const float* __restrict__ hmaps,    // [4,1,540,540]
    double* __restrict__ acc)
{
    __shared__ float s_cx[NBOX], s_cy[NBOX], s_c[NBOX], s_s[NBOX];
    __shared__ float s_hw[NBOX], s_hl[NBOX], s_hv[NBOX];
    __shared__ int   s_sel[NBOX];
    __shared__ int   s_nsel;
    __shared__ float s_red[3][4];

    const int b    = blockIdx.y;
    const int tile = blockIdx.x;
    const int tx0  = (tile % TPX) * TILE;
    const int ty0  = (tile / TPX) * TILE;
    const int tid  = threadIdx.x;

    // ---- per-box constants + tile culling (wave 0 only; order-preserving compact) ----
    if (tid < NBOX) {
        const float* bx = boxes + (b * NBOX + tid) * 7;
        float b0 = bx[0], b1 = bx[1], b3 = bx[3], b4 = bx[4], b5 = bx[5], b6 = bx[6];
        float cx = (b0 - (-54.0f)) / 0.2f;
        float cy = (b1 - (-54.0f)) / 0.2f;
        float hw = (b3 / 0.2f) * 0.5f;
        float hl = (b4 / 0.2f) * 0.5f;
        float c  = cosf(-b6);
        float s  = sinf(-b6);
        float hv = b5 / 5.0f;   // h / (PC_RANGE[5] + 2.0) = h / 5
        s_cx[tid] = cx; s_cy[tid] = cy; s_c[tid] = c; s_s[tid] = s;
        s_hw[tid] = hw; s_hl[tid] = hl; s_hv[tid] = hv;

        // exact AABB of the rotated rect (inverse rotation: dx = lx*c + ly*s, dy = -lx*s + ly*c)
        float ex = fabsf(hw * c) + fabsf(hl * s);
        float ey = fabsf(hw * s) + fabsf(hl * c);
        bool hit = (cx + ex >= (float)tx0) && (cx - ex <= (float)(tx0 + TILE - 1)) &&
                   (cy + ey >= (float)ty0) && (cy - ey <= (float)(ty0 + TILE - 1));
        unsigned long long m = __ballot(hit);
        if (hit) {
            int pos = __popcll(m & ((1ull << tid) - 1ull));
            s_sel[pos] = tid;   // ascending j order preserved -> "last box wins" intact
        }
        if (tid == 0) s_nsel = __popcll(m);
    }
    __syncthreads();
    const int nsel = s_nsel;

    float a1 = 0.0f, a2 = 0.0f, ac = 0.0f;

    for (int i = tid; i < CELLS_PER_TILE; i += 256) {
        const int x = tx0 + (i % TILE);
        const int y = ty0 + (i / TILE);
        const float xg = (float)x, yg = (float)y;

        // rasterize: last covering box wins
        float gt = 0.0f;
        for (int k = 0; k < nsel; ++k) {
            const int j = s_sel[k];
            float dx = xg - s_cx[j];
            float dy = yg - s_cy[j];
            float lx = dx * s_c[j] - dy * s_s[j];
            float ly = dx * s_s[j] + dy * s_c[j];
            if (fabsf(lx) <= s_hw[j] && fabsf(ly) <= s_hl[j]) gt = s_hv[j];
        }

        const int idx = (b * YS + y) * XS + x;
        const float xv = logits[idx];
        const float hm = hmaps[idx];

        const bool pos = gt > 0.0f;                 // neg == !pos (gt is 0 or hv>0)
        const float weight = pos ? 5.0f : 0.1f;
        const bool point = hm > 0.0f;
        const float valid = (pos || point) ? 1.0f : 0.0f;   // pos | (neg & point)

        // bce = max(x,0) - x*gt + log1p(exp(-|x|))
        const float bce = fmaxf(xv, 0.0f) - xv * gt + log1pf(expf(-fabsf(xv)));

        const float p  = 1.0f / (1.0f + expf(-xv));
        const float pt = p * gt + (1.0f - p) * (1.0f - gt);
        const float aw = 0.25f * gt + 0.75f * (1.0f - gt);
        const float om = 1.0f - pt;
        const float fw = om * om * aw * weight;

        a1 += weight * bce * valid;
        a2 += fw * bce * valid;
        ac += valid;
    }

    // ---- block reduction: wave64 shuffle + cross-wave LDS ----
    for (int off = 32; off > 0; off >>= 1) {
        a1 += __shfl_down(a1, off);
        a2 += __shfl_down(a2, off);
        ac += __shfl_down(ac, off);
    }
    const int wave = tid >> 6;
    if ((tid & 63) == 0) { s_red[0][wave] = a1; s_red[1][wave] = a2; s_red[2][wave] = ac; }
    __syncthreads();
    if (tid == 0) {
        float t1 = s_red[0][0] + s_red[0][1] + s_red[0][2] + s_red[0][3];
        float t2 = s_red[1][0] + s_red[1][1] + s_red[1][2] + s_red[1][3];
        float t3 = s_red[2][0] + s_red[2][1] + s_red[2][2] + s_red[2][3];
        atomicAdd(&acc[b],     (double)t1);
        atomicAdd(&acc[4 + b], (double)t2);
        atomicAdd(&acc[8 + b], (double)t3);
    }
}

__global__ void hmdl_finalize(const double* __restrict__ acc, float* __restrict__ out)
{
    float total = 0.0f, ns = 0.0f;
    for (int b = 0; b < NB; ++b) {
        float cnt   = (float)acc[8 + b];
        float denom = fmaxf(cnt, 1.0f);
        float bl = (float)acc[b]     / denom;
        float fl = (float)acc[4 + b] / denom;
        float comb = 0.5f * bl + 0.5f * fl;
        bool has = cnt > 0.0f;
        total += has ? comb : 0.0f;
        ns    += has ? 1.0f : 0.0f;
    }
    out[0] = (ns > 0.0f) ? (1.0f * total / fmaxf(ns, 1.0f)) : total;
}

extern "C" void kernel_launch(void* const* d_in, const int* in_sizes, int n_in,
                              void* d_out, int out_size, void* d_ws, size_t ws_size,
                              hipStream_t stream) {
    const float* logits = (const float*)d_in[0];
    const float* boxes  = (const float*)d_in[1];
    const float* hmaps  = (const float*)d_in[2];
    float* out = (float*)d_out;
    double* acc = (double*)d_ws;

    hipMemsetAsync(acc, 0, 12 * sizeof(double), stream);

    dim3 grid(TPX * TPX, NB);
    hmdl_main<<<grid, 256, 0, stream>>>(logits, boxes, hmaps, acc);
    hmdl_finalize<<<1, 1, 0, stream>>>(acc, out);
}

// Round 2
// 70.846 us; speedup vs baseline: 1.2755x; 1.2755x over previous
//
#include <hip/hip_runtime.h>
#include <math.h>

// Problem constants (from reference)
#define XS 540
#define YS 540
#define NB 4            // batch
#define NBOX 64
#define TILE 36         // 36x36 cells per block
#define TPX 15          // 540 / 36
#define NTILE (TPX * TPX)       // 225
#define CELLS_PER_TILE (TILE * TILE)

// d_ws layout: float part[NB][NTILE][4] = { s1 (w*bce*valid), s2 (focal*bce*valid), cnt, pad }
// Every slot is fully written by its owning block -> no zero-init needed.

__global__ __launch_bounds__(256) void hmdl_main(
    const float* __restrict__ logits,   // [4,1,540,540]
    const float* __restrict__ boxes,    // [4,64,7]
    const float* __restrict__ hmaps,    // [4,1,540,540]
    float4* __restrict__ part)          // [NB*NTILE]
{
    __shared__ float s_cx[NBOX], s_cy[NBOX], s_c[NBOX], s_s[NBOX];
    __shared__ float s_hw[NBOX], s_hl[NBOX], s_hv[NBOX];
    __shared__ int   s_sel[NBOX];
    __shared__ int   s_nsel;
    __shared__ float s_red[3][4];

    const int b    = blockIdx.y;
    const int tile = blockIdx.x;
    const int tx0  = (tile % TPX) * TILE;
    const int ty0  = (tile / TPX) * TILE;
    const int tid  = threadIdx.x;

    // ---- per-box constants + tile culling (wave 0 only; order-preserving compact) ----
    if (tid < NBOX) {
        const float* bx = boxes + (b * NBOX + tid) * 7;
        float b0 = bx[0], b1 = bx[1], b3 = bx[3], b4 = bx[4], b5 = bx[5], b6 = bx[6];
        float cx = (b0 - (-54.0f)) / 0.2f;
        float cy = (b1 - (-54.0f)) / 0.2f;
        float hw = (b3 / 0.2f) * 0.5f;
        float hl = (b4 / 0.2f) * 0.5f;
        float c  = cosf(-b6);
        float s  = sinf(-b6);
        float hv = b5 / 5.0f;   // h / (PC_RANGE[5] + 2.0) = h / 5
        s_cx[tid] = cx; s_cy[tid] = cy; s_c[tid] = c; s_s[tid] = s;
        s_hw[tid] = hw; s_hl[tid] = hl; s_hv[tid] = hv;

        // exact AABB of the rotated rect
        float ex = fabsf(hw * c) + fabsf(hl * s);
        float ey = fabsf(hw * s) + fabsf(hl * c);
        bool hit = (cx + ex >= (float)tx0) && (cx - ex <= (float)(tx0 + TILE - 1)) &&
                   (cy + ey >= (float)ty0) && (cy - ey <= (float)(ty0 + TILE - 1));
        unsigned long long m = __ballot(hit);
        if (hit) {
            int pos = __popcll(m & ((1ull << tid) - 1ull));
            s_sel[pos] = tid;   // ascending j order preserved -> "last box wins" intact
        }
        if (tid == 0) s_nsel = __popcll(m);
    }
    __syncthreads();
    const int nsel = s_nsel;

    float a1 = 0.0f, a2 = 0.0f, ac = 0.0f;

    for (int i = tid; i < CELLS_PER_TILE; i += 256) {
        const int x = tx0 + (i % TILE);
        const int y = ty0 + (i / TILE);
        const float xg = (float)x, yg = (float)y;

        // rasterize: last covering box wins
        float gt = 0.0f;
        for (int k = 0; k < nsel; ++k) {
            const int j = s_sel[k];
            float dx = xg - s_cx[j];
            float dy = yg - s_cy[j];
            float lx = dx * s_c[j] - dy * s_s[j];
            float ly = dx * s_s[j] + dy * s_c[j];
            if (fabsf(lx) <= s_hw[j] && fabsf(ly) <= s_hl[j]) gt = s_hv[j];
        }

        const int idx = (b * YS + y) * XS + x;
        const float xv = logits[idx];
        const float hm = hmaps[idx];

        const bool pos = gt > 0.0f;                 // neg == !pos (gt is 0 or hv>0)
        const float weight = pos ? 5.0f : 0.1f;
        const bool point = hm > 0.0f;
        const float valid = (pos || point) ? 1.0f : 0.0f;   // pos | (neg & point)

        // One transcendental pair per cell:
        //   t = e^{-|x|};  log1p(t) via fast log (|err| ~ulp, threshold is 9.5e-3)
        //   sigmoid(x) = x>=0 ? 1/(1+t) : t/(1+t)
        const float t  = __expf(-fabsf(xv));
        const float bce = fmaxf(xv, 0.0f) - xv * gt + __logf(1.0f + t);
        const float r  = 1.0f / (1.0f + t);
        const float p  = (xv >= 0.0f) ? r : (t * r);
        const float pt = p * gt + (1.0f - p) * (1.0f - gt);
        const float aw = 0.25f * gt + 0.75f * (1.0f - gt);
        const float om = 1.0f - pt;
        const float fw = om * om * aw * weight;

        a1 += weight * bce * valid;
        a2 += fw * bce * valid;
        ac += valid;
    }

    // ---- block reduction: wave64 shuffle + cross-wave LDS ----
    for (int off = 32; off > 0; off >>= 1) {
        a1 += __shfl_down(a1, off);
        a2 += __shfl_down(a2, off);
        ac += __shfl_down(ac, off);
    }
    const int wave = tid >> 6;
    if ((tid & 63) == 0) { s_red[0][wave] = a1; s_red[1][wave] = a2; s_red[2][wave] = ac; }
    __syncthreads();
    if (tid == 0) {
        float t1 = s_red[0][0] + s_red[0][1] + s_red[0][2] + s_red[0][3];
        float t2 = s_red[1][0] + s_red[1][1] + s_red[1][2] + s_red[1][3];
        float t3 = s_red[2][0] + s_red[2][1] + s_red[2][2] + s_red[2][3];
        part[b * NTILE + tile] = make_float4(t1, t2, t3, 0.0f);
    }
}

// One block, 256 threads: wave w reduces sample w's 225 tile-partials.
__global__ __launch_bounds__(256) void hmdl_finalize(
    const float4* __restrict__ part, float* __restrict__ out)
{
    __shared__ float s_comb[NB];
    __shared__ float s_has[NB];

    const int tid  = threadIdx.x;
    const int b    = tid >> 6;
    const int lane = tid & 63;

    double d1 = 0.0, d2 = 0.0, d3 = 0.0;
    for (int t = lane; t < NTILE; t += 64) {
        float4 v = part[b * NTILE + t];
        d1 += (double)v.x; d2 += (double)v.y; d3 += (double)v.z;
    }
    for (int off = 32; off > 0; off >>= 1) {
        d1 += __shfl_down(d1, off);
        d2 += __shfl_down(d2, off);
        d3 += __shfl_down(d3, off);
    }
    if (lane == 0) {
        float cnt   = (float)d3;
        float denom = fmaxf(cnt, 1.0f);
        float bl = (float)d1 / denom;
        float fl = (float)d2 / denom;
        bool has = cnt > 0.0f;
        s_comb[b] = has ? (0.5f * bl + 0.5f * fl) : 0.0f;
        s_has[b]  = has ? 1.0f : 0.0f;
    }
    __syncthreads();
    if (tid == 0) {
        float total = s_comb[0] + s_comb[1] + s_comb[2] + s_comb[3];
        float ns    = s_has[0] + s_has[1] + s_has[2] + s_has[3];
        out[0] = (ns > 0.0f) ? (total / fmaxf(ns, 1.0f)) : total;
    }
}

extern "C" void kernel_launch(void* const* d_in, const int* in_sizes, int n_in,
                              void* d_out, int out_size, void* d_ws, size_t ws_size,
                              hipStream_t stream) {
    const float* logits = (const float*)d_in[0];
    const float* boxes  = (const float*)d_in[1];
    const float* hmaps  = (const float*)d_in[2];
    float* out = (float*)d_out;
    float4* part = (float4*)d_ws;

    dim3 grid(NTILE, NB);
    hmdl_main<<<grid, 256, 0, stream>>>(logits, boxes, hmaps, part);
    hmdl_finalize<<<1, 256, 0, stream>>>(part, out);
}